// Round 1
// baseline (1448.337 us; speedup 1.0000x reference)
//
#include <hip/hip_runtime.h>

#define E_NUM 8
#define DIM   1024
#define HDIM  2048
#define N_TOK 16384
#define NKA   32768
#define CAP   5120

typedef __bf16 bf16x8 __attribute__((ext_vector_type(8)));
typedef float  f32x4  __attribute__((ext_vector_type(4)));

__device__ __forceinline__ unsigned short f2b(float f) {
  union { float f; unsigned u; } v; v.f = f;
  unsigned r = (v.u + 0x7FFFu + ((v.u >> 16) & 1u)) >> 16;  // RNE
  return (unsigned short)r;
}

// ---------------- routing: one wave per token, 64 tokens per block ----------
__global__ __launch_bounds__(256) void routing_kernel(
    const float* __restrict__ x, const float* __restrict__ gate_w,
    int* __restrict__ cnt, float* __restrict__ p_sum,
    int* __restrict__ tok_of_slot, float* __restrict__ w_of_slot) {
  __shared__ float p_acc[E_NUM];
  __shared__ int   lcnt[E_NUM];
  __shared__ int   l_tok[E_NUM][128];
  __shared__ float l_w[E_NUM][128];
  __shared__ int   base[E_NUM];

  int t = threadIdx.x, lane = t & 63, wave = t >> 6;
  if (t < E_NUM) { p_acc[t] = 0.f; lcnt[t] = 0; }
  __syncthreads();

  for (int it = 0; it < 16; ++it) {
    int token = blockIdx.x * 64 + it * 4 + wave;
    const float4* xr = (const float4*)(x + (size_t)token * DIM);
    float4 xv[4];
    #pragma unroll
    for (int i = 0; i < 4; ++i) xv[i] = xr[lane + 64 * i];
    float s[E_NUM];
    #pragma unroll
    for (int e = 0; e < E_NUM; ++e) {
      const float4* gr = (const float4*)(gate_w + e * DIM);
      float acc = 0.f;
      #pragma unroll
      for (int i = 0; i < 4; ++i) {
        float4 g = gr[lane + 64 * i];
        acc += xv[i].x * g.x + xv[i].y * g.y + xv[i].z * g.z + xv[i].w * g.w;
      }
      s[e] = acc;
    }
    #pragma unroll
    for (int e = 0; e < E_NUM; ++e) {
      float v = s[e];
      #pragma unroll
      for (int off = 32; off; off >>= 1) v += __shfl_down(v, off);
      s[e] = v;
    }
    if (lane == 0) {
      float m = s[0];
      #pragma unroll
      for (int e = 1; e < E_NUM; ++e) m = fmaxf(m, s[e]);
      float p[E_NUM]; float sum = 0.f;
      #pragma unroll
      for (int e = 0; e < E_NUM; ++e) { p[e] = expf(s[e] - m); sum += p[e]; }
      float inv = 1.f / sum;
      #pragma unroll
      for (int e = 0; e < E_NUM; ++e) p[e] *= inv;
      // top-2, ties -> lowest index (jax.lax.top_k semantics)
      int e0 = 0; float v0 = p[0];
      #pragma unroll
      for (int e = 1; e < E_NUM; ++e) if (p[e] > v0) { v0 = p[e]; e0 = e; }
      int e1 = -1; float v1 = -1.f;
      #pragma unroll
      for (int e = 0; e < E_NUM; ++e) if (e != e0 && p[e] > v1) { v1 = p[e]; e1 = e; }
      float denom = v0 + v1 + 1e-9f;
      float w0 = v0 / denom, w1 = v1 / denom;
      #pragma unroll
      for (int e = 0; e < E_NUM; ++e) atomicAdd(&p_acc[e], p[e]);
      int i0 = atomicAdd(&lcnt[e0], 1); l_tok[e0][i0] = token; l_w[e0][i0] = w0;
      int i1 = atomicAdd(&lcnt[e1], 1); l_tok[e1][i1] = token; l_w[e1][i1] = w1;
    }
  }
  __syncthreads();
  if (t < E_NUM) {
    base[t] = atomicAdd(&cnt[t], lcnt[t]);
    atomicAdd(&p_sum[t], p_acc[t]);
  }
  __syncthreads();
  int e = t >> 5, i0 = t & 31;
  int n = lcnt[e], b = base[e];
  for (int i = i0; i < n; i += 32) {
    int pos = b + i;
    if (pos < CAP) {
      tok_of_slot[e * CAP + pos] = l_tok[e][i];
      w_of_slot[e * CAP + pos]   = l_w[e][i];
    }
  }
}

// ---------------- loss --------------------------------------------------------
__global__ void loss_kernel(const int* __restrict__ cnt,
                            const float* __restrict__ p_sum,
                            float* __restrict__ out_loss) {
  if (threadIdx.x == 0) {
    float acc = 0.f;
    for (int e = 0; e < E_NUM; ++e)
      acc += (p_sum[e] / (float)N_TOK) * ((float)cnt[e] / (float)NKA);
    *out_loss = (float)E_NUM * acc;
  }
}

// ---------------- GEMM1: h = silu(X W1^T) * (X Wg^T), bf16 out ---------------
__global__ __launch_bounds__(256, 2) void gemm1_kernel(
    const float* __restrict__ x, const float* __restrict__ fc1_w,
    const float* __restrict__ gating_w, const int* __restrict__ cnt,
    const int* __restrict__ tok_of_slot, unsigned short* __restrict__ Hbuf) {
  int e = blockIdx.z;
  int cntc = min(cnt[e], CAP);
  int m0 = blockIdx.y * 128;
  if (m0 >= cntc) return;
  int n0 = blockIdx.x * 128;

  __shared__ __align__(16) unsigned short As[128][40];
  __shared__ __align__(16) unsigned short B1s[128][40];
  __shared__ __align__(16) unsigned short B2s[128][40];

  int t = threadIdx.x;
  int lane = t & 63, wave = t >> 6;
  int wm = (wave >> 1) * 64, wn = (wave & 1) * 64;
  int quad = lane >> 4, r = lane & 15;

  const float* w1e = fc1_w    + (size_t)e * HDIM * DIM;
  const float* wge = gating_w + (size_t)e * HDIM * DIM;

  int tokc[4];
  #pragma unroll
  for (int i = 0; i < 4; ++i) {
    int row = (t + i * 256) >> 3;
    int slot = m0 + row;
    tokc[i] = (slot < cntc) ? tok_of_slot[e * CAP + slot] : -1;
  }

  f32x4 acc1[4][4], acc2[4][4];
  #pragma unroll
  for (int mt = 0; mt < 4; ++mt)
    #pragma unroll
    for (int nt = 0; nt < 4; ++nt) { acc1[mt][nt] = (f32x4)0.f; acc2[mt][nt] = (f32x4)0.f; }

  for (int k0 = 0; k0 < DIM; k0 += 32) {
    #pragma unroll
    for (int i = 0; i < 4; ++i) {
      int f = t + i * 256;
      int row = f >> 3, c4 = (f & 7) * 4;
      float4 a = make_float4(0.f, 0.f, 0.f, 0.f);
      if (tokc[i] >= 0) a = *(const float4*)(x + (size_t)tokc[i] * DIM + k0 + c4);
      float4 b1 = *(const float4*)(w1e + (size_t)(n0 + row) * DIM + k0 + c4);
      float4 b2 = *(const float4*)(wge + (size_t)(n0 + row) * DIM + k0 + c4);
      ushort4 ua = { f2b(a.x), f2b(a.y), f2b(a.z), f2b(a.w) };
      ushort4 u1 = { f2b(b1.x), f2b(b1.y), f2b(b1.z), f2b(b1.w) };
      ushort4 u2 = { f2b(b2.x), f2b(b2.y), f2b(b2.z), f2b(b2.w) };
      *(ushort4*)&As[row][c4]  = ua;
      *(ushort4*)&B1s[row][c4] = u1;
      *(ushort4*)&B2s[row][c4] = u2;
    }
    __syncthreads();
    bf16x8 af[4], b1f[4], b2f[4];
    #pragma unroll
    for (int mt = 0; mt < 4; ++mt)
      af[mt] = *(const bf16x8*)&As[wm + mt * 16 + r][quad * 8];
    #pragma unroll
    for (int nt = 0; nt < 4; ++nt) {
      b1f[nt] = *(const bf16x8*)&B1s[wn + nt * 16 + r][quad * 8];
      b2f[nt] = *(const bf16x8*)&B2s[wn + nt * 16 + r][quad * 8];
    }
    #pragma unroll
    for (int mt = 0; mt < 4; ++mt)
      #pragma unroll
      for (int nt = 0; nt < 4; ++nt) {
        acc1[mt][nt] = __builtin_amdgcn_mfma_f32_16x16x32_bf16(af[mt], b1f[nt], acc1[mt][nt], 0, 0, 0);
        acc2[mt][nt] = __builtin_amdgcn_mfma_f32_16x16x32_bf16(af[mt], b2f[nt], acc2[mt][nt], 0, 0, 0);
      }
    __syncthreads();
  }

  #pragma unroll
  for (int mt = 0; mt < 4; ++mt) {
    #pragma unroll
    for (int reg = 0; reg < 4; ++reg) {
      int row = m0 + wm + mt * 16 + quad * 4 + reg;
      if (row >= cntc) continue;
      size_t basei = (size_t)(e * CAP + row) * HDIM + n0;
      #pragma unroll
      for (int nt = 0; nt < 4; ++nt) {
        float a = acc1[mt][nt][reg];
        float b = acc2[mt][nt][reg];
        float h = (a / (1.f + __expf(-a))) * b;   // silu(a) * b
        Hbuf[basei + wn + nt * 16 + r] = f2b(h);
      }
    }
  }
}

// ---------------- GEMM2: out += w * (H W2^T), atomic combine -----------------
__global__ __launch_bounds__(256, 2) void gemm2_kernel(
    const unsigned short* __restrict__ Hbuf, const float* __restrict__ fc2_w,
    const int* __restrict__ cnt, const int* __restrict__ tok_of_slot,
    const float* __restrict__ w_of_slot, float* __restrict__ out) {
  int e = blockIdx.z;
  int cntc = min(cnt[e], CAP);
  int m0 = blockIdx.y * 128;
  if (m0 >= cntc) return;
  int n0 = blockIdx.x * 128;

  __shared__ __align__(16) unsigned short As[128][40];
  __shared__ __align__(16) unsigned short Bs[128][40];

  int t = threadIdx.x;
  int lane = t & 63, wave = t >> 6;
  int wm = (wave >> 1) * 64, wn = (wave & 1) * 64;
  int quad = lane >> 4, r = lane & 15;

  const float* w2e = fc2_w + (size_t)e * DIM * HDIM;

  f32x4 acc[4][4];
  #pragma unroll
  for (int mt = 0; mt < 4; ++mt)
    #pragma unroll
    for (int nt = 0; nt < 4; ++nt) acc[mt][nt] = (f32x4)0.f;

  for (int k0 = 0; k0 < HDIM; k0 += 32) {
    #pragma unroll
    for (int i = 0; i < 2; ++i) {      // A: 128x32 bf16 from Hbuf (16B per thread-op)
      int f = t + i * 256;
      int row = f >> 2, o = (f & 3) * 8;
      *(uint4*)&As[row][o] =
          *(const uint4*)(Hbuf + (size_t)(e * CAP + m0 + row) * HDIM + k0 + o);
    }
    #pragma unroll
    for (int i = 0; i < 4; ++i) {      // B: 128x32 fp32 -> bf16
      int f = t + i * 256;
      int row = f >> 3, c4 = (f & 7) * 4;
      float4 b = *(const float4*)(w2e + (size_t)(n0 + row) * HDIM + k0 + c4);
      ushort4 ub = { f2b(b.x), f2b(b.y), f2b(b.z), f2b(b.w) };
      *(ushort4*)&Bs[row][c4] = ub;
    }
    __syncthreads();
    bf16x8 af[4], bf[4];
    #pragma unroll
    for (int mt = 0; mt < 4; ++mt)
      af[mt] = *(const bf16x8*)&As[wm + mt * 16 + r][quad * 8];
    #pragma unroll
    for (int nt = 0; nt < 4; ++nt)
      bf[nt] = *(const bf16x8*)&Bs[wn + nt * 16 + r][quad * 8];
    #pragma unroll
    for (int mt = 0; mt < 4; ++mt)
      #pragma unroll
      for (int nt = 0; nt < 4; ++nt)
        acc[mt][nt] = __builtin_amdgcn_mfma_f32_16x16x32_bf16(af[mt], bf[nt], acc[mt][nt], 0, 0, 0);
    __syncthreads();
  }

  #pragma unroll
  for (int mt = 0; mt < 4; ++mt) {
    #pragma unroll
    for (int reg = 0; reg < 4; ++reg) {
      int row = m0 + wm + mt * 16 + quad * 4 + reg;
      if (row >= cntc) continue;
      int tok = tok_of_slot[e * CAP + row];
      float w = w_of_slot[e * CAP + row];
      float* orow = out + (size_t)tok * DIM + n0;
      #pragma unroll
      for (int nt = 0; nt < 4; ++nt)
        atomicAdd(&orow[wn + nt * 16 + r], acc[mt][nt][reg] * w);
    }
  }
}

// ---------------- launch ------------------------------------------------------
extern "C" void kernel_launch(void* const* d_in, const int* in_sizes, int n_in,
                              void* d_out, int out_size, void* d_ws, size_t ws_size,
                              hipStream_t stream) {
  const float* x        = (const float*)d_in[0];
  const float* gate_w   = (const float*)d_in[1];
  const float* fc1_w    = (const float*)d_in[2];
  const float* gating_w = (const float*)d_in[3];
  const float* fc2_w    = (const float*)d_in[4];
  float* out = (float*)d_out;

  char* ws = (char*)d_ws;
  int*   cnt         = (int*)ws;                       // 8 ints
  float* p_sum       = (float*)(ws + 128);             // 8 floats
  int*   tok_of_slot = (int*)(ws + 256);               // 40960 ints
  float* w_of_slot   = (float*)(ws + 256 + 163840);    // 40960 floats
  unsigned short* Hbuf = (unsigned short*)(ws + 256 + 2 * 163840); // 40960x2048 bf16

  hipMemsetAsync(ws, 0, 256, stream);                                  // cnt + p_sum
  hipMemsetAsync(d_out, 0, (size_t)out_size * sizeof(float), stream);  // atomic combine target

  routing_kernel<<<256, 256, 0, stream>>>(x, gate_w, cnt, p_sum, tok_of_slot, w_of_slot);
  loss_kernel<<<1, 64, 0, stream>>>(cnt, p_sum, out + (size_t)N_TOK * DIM);
  gemm1_kernel<<<dim3(16, 40, 8), 256, 0, stream>>>(x, fc1_w, gating_w, cnt, tok_of_slot, Hbuf);
  gemm2_kernel<<<dim3(8, 40, 8), 256, 0, stream>>>(Hbuf, fc2_w, cnt, tok_of_slot, w_of_slot, out);
}

// Round 3
// 999.650 us; speedup vs baseline: 1.4488x; 1.4488x over previous
//
#include <hip/hip_runtime.h>

#define E_NUM 8
#define DIM   1024
#define HDIM  2048
#define N_TOK 16384
#define NKA   32768
#define CAP   5120
#define REG_SZ 16777216  // elements per precast region (8*2048*1024 == 16384*1024)

typedef __bf16 bf16x8 __attribute__((ext_vector_type(8)));
typedef float  f32x4  __attribute__((ext_vector_type(4)));

__device__ __forceinline__ unsigned short f2b(float f) {
  union { float f; unsigned u; } v; v.f = f;
  unsigned r = (v.u + 0x7FFFu + ((v.u >> 16) & 1u)) >> 16;  // RNE
  return (unsigned short)r;
}

// async global->LDS, 16B per lane; LDS dest is wave-uniform base + lane*16
__device__ __forceinline__ void gload16(const void* g, void* l) {
  __builtin_amdgcn_global_load_lds(
      (const __attribute__((address_space(1))) unsigned int*)g,
      (__attribute__((address_space(3))) unsigned int*)l, 16, 0, 0);
}

// ---------------- precast fp32 -> bf16 (W1 | Wg | W2 | X), 4 regions ---------
__global__ __launch_bounds__(256) void cast_kernel(
    const float* __restrict__ s0, const float* __restrict__ s1,
    const float* __restrict__ s2, const float* __restrict__ s3,
    unsigned short* __restrict__ dst) {
  int region = blockIdx.y;
  const float* src = region == 0 ? s0 : region == 1 ? s1 : region == 2 ? s2 : s3;
  size_t i = ((size_t)blockIdx.x * 256 + threadIdx.x) * 8;
  float4 v0 = *(const float4*)(src + i);
  float4 v1 = *(const float4*)(src + i + 4);
  ushort4 u0 = { f2b(v0.x), f2b(v0.y), f2b(v0.z), f2b(v0.w) };
  ushort4 u1 = { f2b(v1.x), f2b(v1.y), f2b(v1.z), f2b(v1.w) };
  unsigned short* o = dst + (size_t)region * REG_SZ + i;
  *(ushort4*)o = u0;
  *(ushort4*)(o + 4) = u1;
}

// ---------------- routing: one wave per token, 64 tokens per block ----------
__global__ __launch_bounds__(256) void routing_kernel(
    const float* __restrict__ x, const float* __restrict__ gate_w,
    int* __restrict__ cnt, float* __restrict__ p_sum,
    int* __restrict__ tok_of_slot, float* __restrict__ w_of_slot) {
  __shared__ float p_acc[E_NUM];
  __shared__ int   lcnt[E_NUM];
  __shared__ int   l_tok[E_NUM][128];
  __shared__ float l_w[E_NUM][128];
  __shared__ int   base[E_NUM];

  int t = threadIdx.x, lane = t & 63, wave = t >> 6;
  if (t < E_NUM) { p_acc[t] = 0.f; lcnt[t] = 0; }
  __syncthreads();

  for (int it = 0; it < 16; ++it) {
    int token = blockIdx.x * 64 + it * 4 + wave;
    const float4* xr = (const float4*)(x + (size_t)token * DIM);
    float4 xv[4];
    #pragma unroll
    for (int i = 0; i < 4; ++i) xv[i] = xr[lane + 64 * i];
    float s[E_NUM];
    #pragma unroll
    for (int e = 0; e < E_NUM; ++e) {
      const float4* gr = (const float4*)(gate_w + e * DIM);
      float acc = 0.f;
      #pragma unroll
      for (int i = 0; i < 4; ++i) {
        float4 g = gr[lane + 64 * i];
        acc += xv[i].x * g.x + xv[i].y * g.y + xv[i].z * g.z + xv[i].w * g.w;
      }
      s[e] = acc;
    }
    #pragma unroll
    for (int e = 0; e < E_NUM; ++e) {
      float v = s[e];
      #pragma unroll
      for (int off = 32; off; off >>= 1) v += __shfl_down(v, off);
      s[e] = v;
    }
    if (lane == 0) {
      float m = s[0];
      #pragma unroll
      for (int e = 1; e < E_NUM; ++e) m = fmaxf(m, s[e]);
      float p[E_NUM]; float sum = 0.f;
      #pragma unroll
      for (int e = 0; e < E_NUM; ++e) { p[e] = expf(s[e] - m); sum += p[e]; }
      float inv = 1.f / sum;
      #pragma unroll
      for (int e = 0; e < E_NUM; ++e) p[e] *= inv;
      int e0 = 0; float v0 = p[0];
      #pragma unroll
      for (int e = 1; e < E_NUM; ++e) if (p[e] > v0) { v0 = p[e]; e0 = e; }
      int e1 = -1; float v1 = -1.f;
      #pragma unroll
      for (int e = 0; e < E_NUM; ++e) if (e != e0 && p[e] > v1) { v1 = p[e]; e1 = e; }
      float denom = v0 + v1 + 1e-9f;
      float w0 = v0 / denom, w1 = v1 / denom;
      #pragma unroll
      for (int e = 0; e < E_NUM; ++e) atomicAdd(&p_acc[e], p[e]);
      int i0 = atomicAdd(&lcnt[e0], 1); l_tok[e0][i0] = token; l_w[e0][i0] = w0;
      int i1 = atomicAdd(&lcnt[e1], 1); l_tok[e1][i1] = token; l_w[e1][i1] = w1;
    }
  }
  __syncthreads();
  if (t < E_NUM) {
    base[t] = atomicAdd(&cnt[t], lcnt[t]);
    atomicAdd(&p_sum[t], p_acc[t]);
  }
  __syncthreads();
  int e = t >> 5, i0 = t & 31;
  int n = lcnt[e], b = base[e];
  for (int i = i0; i < n; i += 32) {
    int pos = b + i;
    if (pos < CAP) {
      tok_of_slot[e * CAP + pos] = l_tok[e][i];
      w_of_slot[e * CAP + pos]   = l_w[e][i];
    }
  }
}

// ---------------- loss --------------------------------------------------------
__global__ void loss_kernel(const int* __restrict__ cnt,
                            const float* __restrict__ p_sum,
                            float* __restrict__ out_loss) {
  if (threadIdx.x == 0) {
    float acc = 0.f;
    for (int e = 0; e < E_NUM; ++e)
      acc += (p_sum[e] / (float)N_TOK) * ((float)cnt[e] / (float)NKA);
    *out_loss = (float)E_NUM * acc;
  }
}

// ---------------- GEMM1: H = silu(X W1^T) * (X Wg^T), bf16 out ---------------
// Experts [e_base, e_base+gridDim.z); Hbuf indexed by local expert blockIdx.z
__global__ __launch_bounds__(256, 2) void gemm1_kernel(
    const unsigned short* __restrict__ Wb,   // [W1|Wg|W2|X] bf16 regions
    const int* __restrict__ cnt, const int* __restrict__ tok_of_slot,
    unsigned short* __restrict__ Hbuf, int e_base) {
  int ez = blockIdx.z;
  int e = e_base + ez;
  int cntc = min(cnt[e], CAP);
  int m0 = blockIdx.y * 128;
  if (m0 >= cntc) return;
  int n0 = blockIdx.x * 128;

  __shared__ __align__(16) unsigned short As[128 * 32];
  __shared__ __align__(16) unsigned short B1s[128 * 32];
  __shared__ __align__(16) unsigned short B2s[128 * 32];

  int t = threadIdx.x;
  int lane = t & 63, wave = t >> 6;
  int wm = (wave >> 1) * 64, wn = (wave & 1) * 64;
  int quad = lane >> 4, r = lane & 15;

  const unsigned short* W1e = Wb + (size_t)e * HDIM * DIM;
  const unsigned short* Wge = Wb + REG_SZ + (size_t)e * HDIM * DIM;
  const unsigned short* Xb  = Wb + (size_t)3 * REG_SZ;

  int tokA[2];
  #pragma unroll
  for (int i = 0; i < 2; ++i) {
    int row = i * 64 + (t >> 2);
    int slot = m0 + row;
    tokA[i] = (slot < cntc) ? tok_of_slot[e * CAP + slot] : 0;
  }

  f32x4 acc1[4][4], acc2[4][4];
  #pragma unroll
  for (int mt = 0; mt < 4; ++mt)
    #pragma unroll
    for (int nt = 0; nt < 4; ++nt) { acc1[mt][nt] = (f32x4)0.f; acc2[mt][nt] = (f32x4)0.f; }

  for (int k0 = 0; k0 < DIM; k0 += 32) {
    #pragma unroll
    for (int i = 0; i < 2; ++i) {
      int c = i * 256 + t;
      int row = c >> 2, col = (c & 3) * 8;
      int ldsb = (i * 256 + wave * 64) * 8;   // wave-uniform base (elements)
      gload16(Xb  + (size_t)tokA[i] * DIM + k0 + col,    &As[ldsb]);
      gload16(W1e + (size_t)(n0 + row) * DIM + k0 + col, &B1s[ldsb]);
      gload16(Wge + (size_t)(n0 + row) * DIM + k0 + col, &B2s[ldsb]);
    }
    __syncthreads();

    bf16x8 af[4], b1f[4], b2f[4];
    #pragma unroll
    for (int mt = 0; mt < 4; ++mt)
      af[mt] = *(const bf16x8*)&As[(wm + mt * 16 + r) * 32 + quad * 8];
    #pragma unroll
    for (int nt = 0; nt < 4; ++nt) {
      b1f[nt] = *(const bf16x8*)&B1s[(wn + nt * 16 + r) * 32 + quad * 8];
      b2f[nt] = *(const bf16x8*)&B2s[(wn + nt * 16 + r) * 32 + quad * 8];
    }
    #pragma unroll
    for (int mt = 0; mt < 4; ++mt)
      #pragma unroll
      for (int nt = 0; nt < 4; ++nt) {
        acc1[mt][nt] = __builtin_amdgcn_mfma_f32_16x16x32_bf16(af[mt], b1f[nt], acc1[mt][nt], 0, 0, 0);
        acc2[mt][nt] = __builtin_amdgcn_mfma_f32_16x16x32_bf16(af[mt], b2f[nt], acc2[mt][nt], 0, 0, 0);
      }
    __syncthreads();
  }

  #pragma unroll
  for (int mt = 0; mt < 4; ++mt) {
    #pragma unroll
    for (int reg = 0; reg < 4; ++reg) {
      int row = m0 + wm + mt * 16 + quad * 4 + reg;
      if (row >= cntc) continue;
      size_t basei = (size_t)(ez * CAP + row) * HDIM + n0;
      #pragma unroll
      for (int nt = 0; nt < 4; ++nt) {
        float a = acc1[mt][nt][reg];
        float b = acc2[mt][nt][reg];
        float h = (a / (1.f + __expf(-a))) * b;   // silu(a) * b
        Hbuf[basei + wn + nt * 16 + r] = f2b(h);
      }
    }
  }
}

// ---------------- GEMM2: out += w * (H W2^T), atomic combine -----------------
__global__ __launch_bounds__(256, 2) void gemm2_kernel(
    const unsigned short* __restrict__ Hbuf, const unsigned short* __restrict__ Wb,
    const int* __restrict__ cnt, const int* __restrict__ tok_of_slot,
    const float* __restrict__ w_of_slot, float* __restrict__ out, int e_base) {
  int ez = blockIdx.z;
  int e = e_base + ez;
  int cntc = min(cnt[e], CAP);
  int m0 = blockIdx.y * 128;
  if (m0 >= cntc) return;
  int n0 = blockIdx.x * 128;

  __shared__ __align__(16) unsigned short As[128 * 32];
  __shared__ __align__(16) unsigned short Bs[128 * 32];

  int t = threadIdx.x;
  int lane = t & 63, wave = t >> 6;
  int wm = (wave >> 1) * 64, wn = (wave & 1) * 64;
  int quad = lane >> 4, r = lane & 15;

  const unsigned short* W2e = Wb + (size_t)2 * REG_SZ + (size_t)e * DIM * HDIM;
  const unsigned short* He  = Hbuf + (size_t)(ez * CAP + m0) * HDIM;

  f32x4 acc[4][4];
  #pragma unroll
  for (int mt = 0; mt < 4; ++mt)
    #pragma unroll
    for (int nt = 0; nt < 4; ++nt) acc[mt][nt] = (f32x4)0.f;

  for (int k0 = 0; k0 < HDIM; k0 += 32) {
    #pragma unroll
    for (int i = 0; i < 2; ++i) {
      int c = i * 256 + t;
      int row = c >> 2, col = (c & 3) * 8;
      int ldsb = (i * 256 + wave * 64) * 8;
      gload16(He  + (size_t)row * HDIM + k0 + col,        &As[ldsb]);
      gload16(W2e + (size_t)(n0 + row) * HDIM + k0 + col, &Bs[ldsb]);
    }
    __syncthreads();

    bf16x8 af[4], bf[4];
    #pragma unroll
    for (int mt = 0; mt < 4; ++mt)
      af[mt] = *(const bf16x8*)&As[(wm + mt * 16 + r) * 32 + quad * 8];
    #pragma unroll
    for (int nt = 0; nt < 4; ++nt)
      bf[nt] = *(const bf16x8*)&Bs[(wn + nt * 16 + r) * 32 + quad * 8];
    #pragma unroll
    for (int mt = 0; mt < 4; ++mt)
      #pragma unroll
      for (int nt = 0; nt < 4; ++nt)
        acc[mt][nt] = __builtin_amdgcn_mfma_f32_16x16x32_bf16(af[mt], bf[nt], acc[mt][nt], 0, 0, 0);
    __syncthreads();
  }

  #pragma unroll
  for (int mt = 0; mt < 4; ++mt) {
    #pragma unroll
    for (int reg = 0; reg < 4; ++reg) {
      int row = m0 + wm + mt * 16 + quad * 4 + reg;
      if (row >= cntc) continue;
      int tok = tok_of_slot[e * CAP + row];
      float w = w_of_slot[e * CAP + row];
      float* orow = out + (size_t)tok * DIM + n0;
      #pragma unroll
      for (int nt = 0; nt < 4; ++nt)
        atomicAdd(&orow[wn + nt * 16 + r], acc[mt][nt][reg] * w);
    }
  }
}

// ---------------- launch ------------------------------------------------------
extern "C" void kernel_launch(void* const* d_in, const int* in_sizes, int n_in,
                              void* d_out, int out_size, void* d_ws, size_t ws_size,
                              hipStream_t stream) {
  const float* x        = (const float*)d_in[0];
  const float* gate_w   = (const float*)d_in[1];
  const float* fc1_w    = (const float*)d_in[2];
  const float* gating_w = (const float*)d_in[3];
  const float* fc2_w    = (const float*)d_in[4];
  float* out = (float*)d_out;

  char* ws = (char*)d_ws;
  int*   cnt         = (int*)ws;                       // 8 ints
  float* p_sum       = (float*)(ws + 128);             // 8 floats
  int*   tok_of_slot = (int*)(ws + 256);               // 40960 ints
  float* w_of_slot   = (float*)(ws + 256 + 163840);    // 40960 floats
  unsigned short* Wb   = (unsigned short*)(ws + 256 + 2 * 163840);  // 4 regions bf16 = 128 MiB
  size_t hbuf_off = 256 + 2 * 163840 + (size_t)4 * REG_SZ * 2;      // 134,545,664 B
  unsigned short* Hbuf = (unsigned short*)(ws + hbuf_off);

  // Adapt expert-chunk to available workspace (constant across calls -> graph-safe).
  const size_t per_e = (size_t)CAP * HDIM * 2;  // 20,971,520 B per expert of Hbuf
  int chunkE = 1;
  if (ws_size > hbuf_off + per_e) {
    size_t c = (ws_size - hbuf_off) / per_e;
    chunkE = c >= 8 ? 8 : (int)c;
  }

  hipMemsetAsync(ws, 0, 256, stream);                                  // cnt + p_sum
  hipMemsetAsync(d_out, 0, (size_t)out_size * sizeof(float), stream);  // atomic combine target

  cast_kernel<<<dim3(8192, 4), 256, 0, stream>>>(fc1_w, gating_w, fc2_w, x, Wb);
  routing_kernel<<<256, 256, 0, stream>>>(x, gate_w, cnt, p_sum, tok_of_slot, w_of_slot);
  loss_kernel<<<1, 64, 0, stream>>>(cnt, p_sum, out + (size_t)N_TOK * DIM);

  for (int eb = 0; eb < E_NUM; eb += chunkE) {
    int ne = (E_NUM - eb) < chunkE ? (E_NUM - eb) : chunkE;
    gemm1_kernel<<<dim3(16, 40, ne), 256, 0, stream>>>(Wb, cnt, tok_of_slot, Hbuf, eb);
    gemm2_kernel<<<dim3(8, 40, ne), 256, 0, stream>>>(Hbuf, Wb, cnt, tok_of_slot, w_of_slot, out, eb);
  }
}